// Round 8
// baseline (417.525 us; speedup 1.0000x reference)
//
#include <hip/hip_runtime.h>

#define B_ 4
#define C_ 256
#define N_ 4096
#define D_ 32

typedef __bf16 bf16;
typedef __bf16 bf16x4 __attribute__((ext_vector_type(4)));
typedef __bf16 bf16x8 __attribute__((ext_vector_type(8)));
typedef float f32x4 __attribute__((ext_vector_type(4)));

// ---------------- kernel 0: weight prep — concat W,b to bf16 wt[320][256], f32 bias[320]
__global__ __launch_bounds__(256) void k_prep(
    const float* __restrict__ Wq, const float* __restrict__ bq,
    const float* __restrict__ Wk, const float* __restrict__ bk,
    const float* __restrict__ Wv, const float* __restrict__ bv,
    bf16* __restrict__ wt, float* __restrict__ bias) {
  int r = blockIdx.x, t = threadIdx.x;
  const float* src; float bval;
  if (r < 32)      { src = Wq + (r << 8);        bval = bq[r]; }
  else if (r < 64) { src = Wk + ((r - 32) << 8); bval = bk[r - 32]; }
  else             { src = Wv + ((r - 64) << 8); bval = bv[r - 64]; }
  wt[(r << 8) + t] = (bf16)src[t];
  if (t == 0) bias[r] = bval;
}

// ---------------- kernel 1: fused avgpool(4x4) + q/k/v 1x1-conv GEMM (MFMA)
__global__ __launch_bounds__(1024) void k_fused(const float* __restrict__ x,
    const bf16* __restrict__ wt, const float* __restrict__ bias,
    bf16* __restrict__ qt, bf16* __restrict__ kt, bf16* __restrict__ v) {
  __shared__ bf16 xsb[64][264];   // [n][c], +8 pad
  int tid = threadIdx.x, wave = tid >> 6, l = tid & 63;
  int lg = l >> 4, ll = l & 15;
  int b = blockIdx.x >> 6, hp = blockIdx.x & 63, n0 = hp * 64;

  const float4* x4 = reinterpret_cast<const float4*>(x) +
      ((size_t)((b * 256 + wave * 16) * 256 + hp * 4)) * 64 + l;
  for (int c0 = 0; c0 < 16; c0 += 4) {
    float s[4] = {0.f, 0.f, 0.f, 0.f};
    #pragma unroll
    for (int j = 0; j < 4; ++j) {
      const float4* p = x4 + (size_t)(c0 + j) * 16384;
      #pragma unroll
      for (int dh = 0; dh < 4; ++dh) {
        float4 a = p[dh * 64];
        s[j] += a.x + a.y + a.z + a.w;
      }
    }
    bf16x4 pk;
    #pragma unroll
    for (int j = 0; j < 4; ++j) pk[j] = (bf16)(s[j] * 0.0625f);
    *reinterpret_cast<bf16x4*>(&xsb[l][wave * 16 + c0]) = pk;
  }
  __syncthreads();

  f32x4 acc[2][4];
  #pragma unroll
  for (int j = 0; j < 2; ++j)
    #pragma unroll
    for (int cb = 0; cb < 4; ++cb) acc[j][cb] = (f32x4){0.f, 0.f, 0.f, 0.f};

  for (int kk = 0; kk < 8; ++kk) {
    bf16x8 bfr[4];
    #pragma unroll
    for (int cb = 0; cb < 4; ++cb)
      bfr[cb] = *reinterpret_cast<const bf16x8*>(&xsb[cb * 16 + ll][kk * 32 + lg * 8]);
    #pragma unroll
    for (int j = 0; j < 2; ++j) {
      int rb = wave + j * 16;
      if (rb < 20) {
        bf16x8 afr = *reinterpret_cast<const bf16x8*>(
            wt + ((size_t)(rb * 16 + ll)) * 256 + kk * 32 + lg * 8);
        #pragma unroll
        for (int cb = 0; cb < 4; ++cb)
          acc[j][cb] = __builtin_amdgcn_mfma_f32_16x16x32_bf16(afr, bfr[cb], acc[j][cb], 0, 0, 0);
      }
    }
  }

  #pragma unroll
  for (int j = 0; j < 2; ++j) {
    int rb = wave + j * 16;
    if (rb < 20) {
      int row0 = rb * 16 + lg * 4;
      float4 b4 = *reinterpret_cast<const float4*>(bias + row0);
      #pragma unroll
      for (int cb = 0; cb < 4; ++cb) {
        int n = n0 + cb * 16 + ll;
        float v0 = acc[j][cb][0] + b4.x, v1 = acc[j][cb][1] + b4.y;
        float v2 = acc[j][cb][2] + b4.z, v3 = acc[j][cb][3] + b4.w;
        if (row0 < 32) {
          bf16x4 pk = {(bf16)v0, (bf16)v1, (bf16)v2, (bf16)v3};
          *reinterpret_cast<bf16x4*>(qt + ((size_t)(b * N_ + n)) * D_ + row0) = pk;
        } else if (row0 < 64) {
          bf16x4 pk = {(bf16)v0, (bf16)v1, (bf16)v2, (bf16)v3};
          *reinterpret_cast<bf16x4*>(kt + ((size_t)(b * N_ + n)) * D_ + row0 - 32) = pk;
        } else {
          int c = row0 - 64;
          v[((size_t)(b * 256 + c + 0)) * N_ + n] = (bf16)v0;
          v[((size_t)(b * 256 + c + 1)) * N_ + n] = (bf16)v1;
          v[((size_t)(b * 256 + c + 2)) * N_ + n] = (bf16)v2;
          v[((size_t)(b * 256 + c + 3)) * N_ + n] = (bf16)v3;
        }
      }
    }
  }
}

// ---------------- kernel 3: flash-style attention (exact R5 version)
__global__ __launch_bounds__(1024) void k_attn(const bf16* __restrict__ qt,
    const bf16* __restrict__ kt, const bf16* __restrict__ v,
    float* __restrict__ outs) {
  __shared__ bf16 p_s[2][64][264];       // 2 x (P tile [tn][tm], +8 pad)
  __shared__ float l_red[16][64];
  __shared__ float l_s[64];
  int tid = threadIdx.x, wave = tid >> 6, l = tid & 63;
  int lg = l >> 4, ll = l & 15;
  int blk = blockIdx.x;
  int b  = (blk & 7) >> 1;                       // XCD-pair -> batch (L2 locality)
  int nt = ((blk >> 3) << 1) | (blk & 1);        // 64 query tiles of 64
  int n0 = nt * 64;

  const f32x4 fz = {0.f, 0.f, 0.f, 0.f};

  bf16x8 aq[4];
  #pragma unroll
  for (int tnf = 0; tnf < 4; ++tnf)
    aq[tnf] = *reinterpret_cast<const bf16x8*>(
        qt + ((size_t)(b * N_ + n0 + tnf * 16 + ll)) * D_ + lg * 8);

  f32x4 acc[4];      // [tnf] : out tile [64tn x 16c per wave]
  float lsum[4][4];  // [tnf][r] row-sum partials
  #pragma unroll
  for (int a = 0; a < 4; ++a) {
    acc[a] = fz;
    #pragma unroll
    for (int r = 0; r < 4; ++r) lsum[a][r] = 0.f;
  }

  const int mw = wave * 16;   // QK^T tm band == PV c band
  const int colw = mw + ll;

  // ---- prologue: A(0) into p_s[0]
  {
    bf16x8 bk8 = *reinterpret_cast<const bf16x8*>(
        kt + ((size_t)(b * N_ + colw)) * D_ + lg * 8);
    #pragma unroll
    for (int tnf = 0; tnf < 4; ++tnf) {
      f32x4 e = __builtin_amdgcn_mfma_f32_16x16x32_bf16(aq[tnf], bk8, fz, 0, 0, 0);
      #pragma unroll
      for (int r = 0; r < 4; ++r) {
        float p = __expf(e[r]);
        lsum[tnf][r] += p;
        p_s[0][tnf * 16 + lg * 4 + r][colw] = (bf16)p;
      }
    }
  }
  __syncthreads();

  // ---- main loop: B(t) || A(t+1), one barrier per iter
  for (int t = 0; t < 15; ++t) {
    int m0 = t * 256;
    int cur = t & 1, nxt = cur ^ 1;
    bf16x8 bk8 = *reinterpret_cast<const bf16x8*>(
        kt + ((size_t)(b * N_ + m0 + 256 + colw)) * D_ + lg * 8);
    #pragma unroll
    for (int kk = 0; kk < 8; ++kk) {
      bf16x8 bv8 = *reinterpret_cast<const bf16x8*>(
          v + ((size_t)((b << 8) + colw)) * N_ + m0 + kk * 32 + lg * 8);
      #pragma unroll
      for (int tnf = 0; tnf < 4; ++tnf) {
        bf16x8 pa = *reinterpret_cast<const bf16x8*>(
            &p_s[cur][tnf * 16 + ll][kk * 32 + lg * 8]);
        acc[tnf] = __builtin_amdgcn_mfma_f32_16x16x32_bf16(pa, bv8, acc[tnf], 0, 0, 0);
      }
    }
    #pragma unroll
    for (int tnf = 0; tnf < 4; ++tnf) {
      f32x4 e = __builtin_amdgcn_mfma_f32_16x16x32_bf16(aq[tnf], bk8, fz, 0, 0, 0);
      #pragma unroll
      for (int r = 0; r < 4; ++r) {
        float p = __expf(e[r]);
        lsum[tnf][r] += p;
        p_s[nxt][tnf * 16 + lg * 4 + r][colw] = (bf16)p;
      }
    }
    __syncthreads();
  }
  // ---- tail: B(15) from p_s[1]
  {
    int m0 = 15 * 256;
    #pragma unroll
    for (int kk = 0; kk < 8; ++kk) {
      bf16x8 bv8 = *reinterpret_cast<const bf16x8*>(
          v + ((size_t)((b << 8) + colw)) * N_ + m0 + kk * 32 + lg * 8);
      #pragma unroll
      for (int tnf = 0; tnf < 4; ++tnf) {
        bf16x8 pa = *reinterpret_cast<const bf16x8*>(
            &p_s[1][tnf * 16 + ll][kk * 32 + lg * 8]);
        acc[tnf] = __builtin_amdgcn_mfma_f32_16x16x32_bf16(pa, bv8, acc[tnf], 0, 0, 0);
      }
    }
  }

  // ---- reduce l: over 16 ll lanes (shfl), then over 16 waves (LDS)
  #pragma unroll
  for (int tnf = 0; tnf < 4; ++tnf) {
    #pragma unroll
    for (int r = 0; r < 4; ++r) {
      float s = lsum[tnf][r];
      s += __shfl_xor(s, 1);
      s += __shfl_xor(s, 2);
      s += __shfl_xor(s, 4);
      s += __shfl_xor(s, 8);
      if (ll == 0) l_red[wave][tnf * 16 + lg * 4 + r] = s;
    }
  }
  __syncthreads();
  if (tid < 64) {
    float s = 0.f;
    #pragma unroll
    for (int w = 0; w < 16; ++w) s += l_red[w][tid];
    l_s[tid] = s;
  }
  __syncthreads();

  // ---- normalize + write outs[b][c][n] (float4 over contiguous n)
  #pragma unroll
  for (int tnf = 0; tnf < 4; ++tnf) {
    int tn0 = tnf * 16 + lg * 4;
    float4 o;
    o.x = acc[tnf][0] / l_s[tn0 + 0];
    o.y = acc[tnf][1] / l_s[tn0 + 1];
    o.z = acc[tnf][2] / l_s[tn0 + 2];
    o.w = acc[tnf][3] / l_s[tn0 + 3];
    *reinterpret_cast<float4*>(outs + ((size_t)((b << 8) + colw)) * N_ + n0 + tn0) = o;
  }
}

// ---------------- kernel 4: bilinear upsample x4 + gamma residual.
__global__ __launch_bounds__(256) void k_up(const float* __restrict__ outs,
    const float* __restrict__ x, const float* __restrict__ gamma,
    float* __restrict__ out) {
  __shared__ float s_o[4096];            // outs[bc] as [64][64]
  int tid = threadIdx.x, wave = tid >> 6, tw = tid & 63;
  int bc = blockIdx.x;
  const float* src = outs + (size_t)bc * 4096;
  #pragma unroll
  for (int ch = 0; ch < 4; ++ch)
    *reinterpret_cast<float4*>(&s_o[ch * 1024 + tid * 4]) =
        *reinterpret_cast<const float4*>(src + ch * 1024 + tid * 4);
  __syncthreads();

  float g = gamma[0];
  const float4* xr = reinterpret_cast<const float4*>(x) + (size_t)bc * 16384;
  float4* outr = reinterpret_cast<float4*>(out) + (size_t)bc * 16384;

  int twm = tw == 0 ? 0 : tw - 1;
  int twp = tw == 63 ? 63 : tw + 1;

  for (int hb = 0; hb < 64; ++hb) {
    int h = hb * 4 + wave;
    int th = 2 * h - 3;
    int h0 = th < 0 ? -1 : (th >> 3);
    float fh = (float)(th - 8 * h0) * 0.125f;
    int i0h = h0 < 0 ? 0 : h0;
    int i1h = h0 + 1 > 63 ? 63 : h0 + 1;
    const float* r0 = &s_o[i0h * 64];
    const float* r1 = &s_o[i1h * 64];
    float a_m = r0[twm], a_c = r0[tw], a_p = r0[twp];
    float b_m = r1[twm], b_c = r1[tw], b_p = r1[twp];
    float t0 = a_m + 0.625f * (a_c - a_m), u0 = b_m + 0.625f * (b_c - b_m);
    float t1 = a_m + 0.875f * (a_c - a_m), u1 = b_m + 0.875f * (b_c - b_m);
    float t2 = a_c + 0.125f * (a_p - a_c), u2 = b_c + 0.125f * (b_p - b_c);
    float t3 = a_c + 0.375f * (a_p - a_c), u3 = b_c + 0.375f * (b_p - b_c);
    float4 xv = xr[h * 64 + tw];
    float4 o;
    o.x = g * (t0 + fh * (u0 - t0)) + xv.x;
    o.y = g * (t1 + fh * (u1 - t1)) + xv.y;
    o.z = g * (t2 + fh * (u2 - t2)) + xv.z;
    o.w = g * (t3 + fh * (u3 - t3)) + xv.w;
    outr[h * 64 + tw] = o;
  }
}

extern "C" void kernel_launch(void* const* d_in, const int* in_sizes, int n_in,
                              void* d_out, int out_size, void* d_ws, size_t ws_size,
                              hipStream_t stream) {
  const float* x     = (const float*)d_in[0];
  const float* Wq    = (const float*)d_in[1];
  const float* bq    = (const float*)d_in[2];
  const float* Wk    = (const float*)d_in[3];
  const float* bk    = (const float*)d_in[4];
  const float* Wv    = (const float*)d_in[5];
  const float* bv    = (const float*)d_in[6];
  const float* gamma = (const float*)d_in[7];
  float* out = (float*)d_out;

  char* ws = (char*)d_ws;
  float* outs = (float*)(ws);                         // 16 MiB
  bf16*  v    = (bf16*) (ws + (16u << 20));           // 8 MiB
  bf16*  qt   = (bf16*) (ws + (24u << 20));           // 1 MiB
  bf16*  kt   = (bf16*) (ws + (25u << 20));           // 1 MiB
  bf16*  wt   = (bf16*) (ws + (26u << 20));           // 160 KiB
  float* bias = (float*)(ws + (27u << 20));           // 1.25 KiB

  // DIAGNOSTIC: attn x3 (idempotent) -> dur ~= 253 + 2 * t_attn.
  hipLaunchKernelGGL(k_prep,  dim3(320),  dim3(256),  0, stream,
                     Wq, bq, Wk, bk, Wv, bv, wt, bias);
  hipLaunchKernelGGL(k_fused, dim3(256),  dim3(1024), 0, stream,
                     x, wt, bias, qt, kt, v);
  for (int rep = 0; rep < 3; ++rep)
    hipLaunchKernelGGL(k_attn,  dim3(256),  dim3(1024), 0, stream, qt, kt, v, outs);
  hipLaunchKernelGGL(k_up,    dim3(1024), dim3(256),  0, stream, outs, x, gamma, out);
}

// Round 9
// 402.361 us; speedup vs baseline: 1.0377x; 1.0377x over previous
//
#include <hip/hip_runtime.h>

#define B_ 4
#define C_ 256
#define N_ 4096
#define D_ 32

typedef __bf16 bf16;
typedef __bf16 bf16x4 __attribute__((ext_vector_type(4)));
typedef __bf16 bf16x8 __attribute__((ext_vector_type(8)));
typedef float f32x4 __attribute__((ext_vector_type(4)));

// ---------------- kernel 0: weight prep — concat W,b to bf16 wt[320][256], f32 bias[320]
__global__ __launch_bounds__(256) void k_prep(
    const float* __restrict__ Wq, const float* __restrict__ bq,
    const float* __restrict__ Wk, const float* __restrict__ bk,
    const float* __restrict__ Wv, const float* __restrict__ bv,
    bf16* __restrict__ wt, float* __restrict__ bias) {
  int r = blockIdx.x, t = threadIdx.x;
  const float* src; float bval;
  if (r < 32)      { src = Wq + (r << 8);        bval = bq[r]; }
  else if (r < 64) { src = Wk + ((r - 32) << 8); bval = bk[r - 32]; }
  else             { src = Wv + ((r - 64) << 8); bval = bv[r - 64]; }
  wt[(r << 8) + t] = (bf16)src[t];
  if (t == 0) bias[r] = bval;
}

// ---------------- kernel 1: fused avgpool(4x4) + q/k/v 1x1-conv GEMM (MFMA)
__global__ __launch_bounds__(1024) void k_fused(const float* __restrict__ x,
    const bf16* __restrict__ wt, const float* __restrict__ bias,
    bf16* __restrict__ qt, bf16* __restrict__ kt, bf16* __restrict__ v) {
  __shared__ bf16 xsb[64][264];   // [n][c], +8 pad
  int tid = threadIdx.x, wave = tid >> 6, l = tid & 63;
  int lg = l >> 4, ll = l & 15;
  int b = blockIdx.x >> 6, hp = blockIdx.x & 63, n0 = hp * 64;

  const float4* x4 = reinterpret_cast<const float4*>(x) +
      ((size_t)((b * 256 + wave * 16) * 256 + hp * 4)) * 64 + l;
  for (int c0 = 0; c0 < 16; c0 += 4) {
    float s[4] = {0.f, 0.f, 0.f, 0.f};
    #pragma unroll
    for (int j = 0; j < 4; ++j) {
      const float4* p = x4 + (size_t)(c0 + j) * 16384;
      #pragma unroll
      for (int dh = 0; dh < 4; ++dh) {
        float4 a = p[dh * 64];
        s[j] += a.x + a.y + a.z + a.w;
      }
    }
    bf16x4 pk;
    #pragma unroll
    for (int j = 0; j < 4; ++j) pk[j] = (bf16)(s[j] * 0.0625f);
    *reinterpret_cast<bf16x4*>(&xsb[l][wave * 16 + c0]) = pk;
  }
  __syncthreads();

  f32x4 acc[2][4];
  #pragma unroll
  for (int j = 0; j < 2; ++j)
    #pragma unroll
    for (int cb = 0; cb < 4; ++cb) acc[j][cb] = (f32x4){0.f, 0.f, 0.f, 0.f};

  for (int kk = 0; kk < 8; ++kk) {
    bf16x8 bfr[4];
    #pragma unroll
    for (int cb = 0; cb < 4; ++cb)
      bfr[cb] = *reinterpret_cast<const bf16x8*>(&xsb[cb * 16 + ll][kk * 32 + lg * 8]);
    #pragma unroll
    for (int j = 0; j < 2; ++j) {
      int rb = wave + j * 16;
      if (rb < 20) {
        bf16x8 afr = *reinterpret_cast<const bf16x8*>(
            wt + ((size_t)(rb * 16 + ll)) * 256 + kk * 32 + lg * 8);
        #pragma unroll
        for (int cb = 0; cb < 4; ++cb)
          acc[j][cb] = __builtin_amdgcn_mfma_f32_16x16x32_bf16(afr, bfr[cb], acc[j][cb], 0, 0, 0);
      }
    }
  }

  #pragma unroll
  for (int j = 0; j < 2; ++j) {
    int rb = wave + j * 16;
    if (rb < 20) {
      int row0 = rb * 16 + lg * 4;
      float4 b4 = *reinterpret_cast<const float4*>(bias + row0);
      #pragma unroll
      for (int cb = 0; cb < 4; ++cb) {
        int n = n0 + cb * 16 + ll;
        float v0 = acc[j][cb][0] + b4.x, v1 = acc[j][cb][1] + b4.y;
        float v2 = acc[j][cb][2] + b4.z, v3 = acc[j][cb][3] + b4.w;
        if (row0 < 32) {
          bf16x4 pk = {(bf16)v0, (bf16)v1, (bf16)v2, (bf16)v3};
          *reinterpret_cast<bf16x4*>(qt + ((size_t)(b * N_ + n)) * D_ + row0) = pk;
        } else if (row0 < 64) {
          bf16x4 pk = {(bf16)v0, (bf16)v1, (bf16)v2, (bf16)v3};
          *reinterpret_cast<bf16x4*>(kt + ((size_t)(b * N_ + n)) * D_ + row0 - 32) = pk;
        } else {
          int c = row0 - 64;
          v[((size_t)(b * 256 + c + 0)) * N_ + n] = (bf16)v0;
          v[((size_t)(b * 256 + c + 1)) * N_ + n] = (bf16)v1;
          v[((size_t)(b * 256 + c + 2)) * N_ + n] = (bf16)v2;
          v[((size_t)(b * 256 + c + 3)) * N_ + n] = (bf16)v3;
        }
      }
    }
  }
}

// ---------------- kernel 3: flash-style attention, bf16 MFMA, double-buffered.
// Phase B: 4 n-bands x 4 c-bands wave partition — each wave owns O[16n x 64c]
// and walks all m, so one pa LDS read feeds 4 MFMAs (block LDS reads/iter
// 512 -> 128) and no cross-wave reduction is needed. acc = 16 VGPR (no spill).
__global__ __launch_bounds__(1024) void k_attn(const bf16* __restrict__ qt,
    const bf16* __restrict__ kt, const bf16* __restrict__ v,
    float* __restrict__ outs) {
  __shared__ bf16 p_s[2][64][264];       // 2 x (P tile [tn][tm], +8 pad)
  __shared__ float l_red[16][64];
  __shared__ float l_s[64];
  int tid = threadIdx.x, wave = tid >> 6, l = tid & 63;
  int lg = l >> 4, ll = l & 15;
  int blk = blockIdx.x;
  int b  = (blk & 7) >> 1;                       // XCD-pair -> batch (L2 locality)
  int nt = ((blk >> 3) << 1) | (blk & 1);        // 64 query tiles of 64
  int n0 = nt * 64;

  const f32x4 fz = {0.f, 0.f, 0.f, 0.f};

  bf16x8 aq[4];
  #pragma unroll
  for (int tnf = 0; tnf < 4; ++tnf)
    aq[tnf] = *reinterpret_cast<const bf16x8*>(
        qt + ((size_t)(b * N_ + n0 + tnf * 16 + ll)) * D_ + lg * 8);

  f32x4 acc[4];      // [cf] : O[16n (this n-band) x 64c (this c-band)]
  float lsum[4][4];  // [tnf][r] row-sum partials (phase-A 16-col m-band)
  #pragma unroll
  for (int a = 0; a < 4; ++a) {
    acc[a] = fz;
    #pragma unroll
    for (int r = 0; r < 4; ++r) lsum[a][r] = 0.f;
  }

  const int mw = wave * 16;               // phase A col band
  const int colw = mw + ll;
  const int nb16 = (wave >> 2) * 16;      // phase B n-band base
  const int cw   = (wave & 3) * 64;       // phase B c-band base
  const bf16* vbase = v + ((size_t)(b << 8)) * N_;

  // ---- prologue: A(0) into p_s[0]
  {
    bf16x8 bk8 = *reinterpret_cast<const bf16x8*>(
        kt + ((size_t)(b * N_ + colw)) * D_ + lg * 8);
    #pragma unroll
    for (int tnf = 0; tnf < 4; ++tnf) {
      f32x4 e = __builtin_amdgcn_mfma_f32_16x16x32_bf16(aq[tnf], bk8, fz, 0, 0, 0);
      #pragma unroll
      for (int r = 0; r < 4; ++r) {
        float p = __expf(e[r]);
        lsum[tnf][r] += p;
        p_s[0][tnf * 16 + lg * 4 + r][colw] = (bf16)p;
      }
    }
  }
  __syncthreads();

  // ---- main loop: B(t) || A(t+1), one barrier per iter
  for (int t = 0; t < 15; ++t) {
    int m0 = t * 256;
    int cur = t & 1, nxt = cur ^ 1;
    bf16x8 bk8 = *reinterpret_cast<const bf16x8*>(
        kt + ((size_t)(b * N_ + m0 + 256 + colw)) * D_ + lg * 8);
    // B(t): O[nb16..+16][cw..+64] over m in [m0, m0+256)
    #pragma unroll
    for (int kk = 0; kk < 8; ++kk) {
      int mk = m0 + kk * 32 + lg * 8;
      bf16x8 pa = *reinterpret_cast<const bf16x8*>(
          &p_s[cur][nb16 + ll][kk * 32 + lg * 8]);
      #pragma unroll
      for (int cf = 0; cf < 4; ++cf) {
        bf16x8 bv8 = *reinterpret_cast<const bf16x8*>(
            vbase + ((size_t)(cw + cf * 16 + ll)) * N_ + mk);
        acc[cf] = __builtin_amdgcn_mfma_f32_16x16x32_bf16(pa, bv8, acc[cf], 0, 0, 0);
      }
    }
    // A(t+1)
    #pragma unroll
    for (int tnf = 0; tnf < 4; ++tnf) {
      f32x4 e = __builtin_amdgcn_mfma_f32_16x16x32_bf16(aq[tnf], bk8, fz, 0, 0, 0);
      #pragma unroll
      for (int r = 0; r < 4; ++r) {
        float p = __expf(e[r]);
        lsum[tnf][r] += p;
        p_s[nxt][tnf * 16 + lg * 4 + r][colw] = (bf16)p;
      }
    }
    __syncthreads();
  }
  // ---- tail: B(15) from p_s[1]
  {
    int m0 = 15 * 256;
    #pragma unroll
    for (int kk = 0; kk < 8; ++kk) {
      int mk = m0 + kk * 32 + lg * 8;
      bf16x8 pa = *reinterpret_cast<const bf16x8*>(
          &p_s[1][nb16 + ll][kk * 32 + lg * 8]);
      #pragma unroll
      for (int cf = 0; cf < 4; ++cf) {
        bf16x8 bv8 = *reinterpret_cast<const bf16x8*>(
            vbase + ((size_t)(cw + cf * 16 + ll)) * N_ + mk);
        acc[cf] = __builtin_amdgcn_mfma_f32_16x16x32_bf16(pa, bv8, acc[cf], 0, 0, 0);
      }
    }
  }

  // ---- reduce l: over 16 ll lanes (shfl), then over 16 waves (LDS)
  #pragma unroll
  for (int tnf = 0; tnf < 4; ++tnf) {
    #pragma unroll
    for (int r = 0; r < 4; ++r) {
      float s = lsum[tnf][r];
      s += __shfl_xor(s, 1);
      s += __shfl_xor(s, 2);
      s += __shfl_xor(s, 4);
      s += __shfl_xor(s, 8);
      if (ll == 0) l_red[wave][tnf * 16 + lg * 4 + r] = s;
    }
  }
  __syncthreads();
  if (tid < 64) {
    float s = 0.f;
    #pragma unroll
    for (int w = 0; w < 16; ++w) s += l_red[w][tid];
    l_s[tid] = s;
  }
  __syncthreads();

  // ---- normalize + write outs[b][c][n]: O row = nb16 + lg*4 + r (float4 over n)
  {
    int tn0 = nb16 + lg * 4;
    float4 inv;
    inv.x = 1.0f / l_s[tn0 + 0];
    inv.y = 1.0f / l_s[tn0 + 1];
    inv.z = 1.0f / l_s[tn0 + 2];
    inv.w = 1.0f / l_s[tn0 + 3];
    #pragma unroll
    for (int cf = 0; cf < 4; ++cf) {
      int c = cw + cf * 16 + ll;
      float4 o;
      o.x = acc[cf][0] * inv.x;
      o.y = acc[cf][1] * inv.y;
      o.z = acc[cf][2] * inv.z;
      o.w = acc[cf][3] * inv.w;
      *reinterpret_cast<float4*>(outs + ((size_t)((b << 8) + c)) * N_ + n0 + tn0) = o;
    }
  }
}

// ---------------- kernel 4: bilinear upsample x4 + gamma residual.
__global__ __launch_bounds__(256) void k_up(const float* __restrict__ outs,
    const float* __restrict__ x, const float* __restrict__ gamma,
    float* __restrict__ out) {
  __shared__ float s_o[4096];            // outs[bc] as [64][64]
  int tid = threadIdx.x, wave = tid >> 6, tw = tid & 63;
  int bc = blockIdx.x;
  const float* src = outs + (size_t)bc * 4096;
  #pragma unroll
  for (int ch = 0; ch < 4; ++ch)
    *reinterpret_cast<float4*>(&s_o[ch * 1024 + tid * 4]) =
        *reinterpret_cast<const float4*>(src + ch * 1024 + tid * 4);
  __syncthreads();

  float g = gamma[0];
  const float4* xr = reinterpret_cast<const float4*>(x) + (size_t)bc * 16384;
  float4* outr = reinterpret_cast<float4*>(out) + (size_t)bc * 16384;

  int twm = tw == 0 ? 0 : tw - 1;
  int twp = tw == 63 ? 63 : tw + 1;

  for (int hb = 0; hb < 64; ++hb) {
    int h = hb * 4 + wave;
    int th = 2 * h - 3;
    int h0 = th < 0 ? -1 : (th >> 3);
    float fh = (float)(th - 8 * h0) * 0.125f;
    int i0h = h0 < 0 ? 0 : h0;
    int i1h = h0 + 1 > 63 ? 63 : h0 + 1;
    const float* r0 = &s_o[i0h * 64];
    const float* r1 = &s_o[i1h * 64];
    float a_m = r0[twm], a_c = r0[tw], a_p = r0[twp];
    float b_m = r1[twm], b_c = r1[tw], b_p = r1[twp];
    float t0 = a_m + 0.625f * (a_c - a_m), u0 = b_m + 0.625f * (b_c - b_m);
    float t1 = a_m + 0.875f * (a_c - a_m), u1 = b_m + 0.875f * (b_c - b_m);
    float t2 = a_c + 0.125f * (a_p - a_c), u2 = b_c + 0.125f * (b_p - b_c);
    float t3 = a_c + 0.375f * (a_p - a_c), u3 = b_c + 0.375f * (b_p - b_c);
    float4 xv = xr[h * 64 + tw];
    float4 o;
    o.x = g * (t0 + fh * (u0 - t0)) + xv.x;
    o.y = g * (t1 + fh * (u1 - t1)) + xv.y;
    o.z = g * (t2 + fh * (u2 - t2)) + xv.z;
    o.w = g * (t3 + fh * (u3 - t3)) + xv.w;
    outr[h * 64 + tw] = o;
  }
}

extern "C" void kernel_launch(void* const* d_in, const int* in_sizes, int n_in,
                              void* d_out, int out_size, void* d_ws, size_t ws_size,
                              hipStream_t stream) {
  const float* x     = (const float*)d_in[0];
  const float* Wq    = (const float*)d_in[1];
  const float* bq    = (const float*)d_in[2];
  const float* Wk    = (const float*)d_in[3];
  const float* bk    = (const float*)d_in[4];
  const float* Wv    = (const float*)d_in[5];
  const float* bv    = (const float*)d_in[6];
  const float* gamma = (const float*)d_in[7];
  float* out = (float*)d_out;

  char* ws = (char*)d_ws;
  float* outs = (float*)(ws);                         // 16 MiB
  bf16*  v    = (bf16*) (ws + (16u << 20));           // 8 MiB
  bf16*  qt   = (bf16*) (ws + (24u << 20));           // 1 MiB
  bf16*  kt   = (bf16*) (ws + (25u << 20));           // 1 MiB
  bf16*  wt   = (bf16*) (ws + (26u << 20));           // 160 KiB
  float* bias = (float*)(ws + (27u << 20));           // 1.25 KiB

  hipLaunchKernelGGL(k_prep,  dim3(320),  dim3(256),  0, stream,
                     Wq, bq, Wk, bk, Wv, bv, wt, bias);
  hipLaunchKernelGGL(k_fused, dim3(256),  dim3(1024), 0, stream,
                     x, wt, bias, qt, kt, v);
  hipLaunchKernelGGL(k_attn,  dim3(256),  dim3(1024), 0, stream, qt, kt, v, outs);
  hipLaunchKernelGGL(k_up,    dim3(1024), dim3(256),  0, stream, outs, x, gamma, out);
}

// Round 11
// 248.169 us; speedup vs baseline: 1.6824x; 1.6213x over previous
//
#include <hip/hip_runtime.h>

#define B_ 4
#define C_ 256
#define N_ 4096
#define D_ 32

typedef __bf16 bf16;
typedef __bf16 bf16x4 __attribute__((ext_vector_type(4)));
typedef __bf16 bf16x8 __attribute__((ext_vector_type(8)));
typedef float f32x4 __attribute__((ext_vector_type(4)));

// ---------------- kernel 0: weight prep — concat W,b to bf16 wt[320][256], f32 bias[320]
__global__ __launch_bounds__(256) void k_prep(
    const float* __restrict__ Wq, const float* __restrict__ bq,
    const float* __restrict__ Wk, const float* __restrict__ bk,
    const float* __restrict__ Wv, const float* __restrict__ bv,
    bf16* __restrict__ wt, float* __restrict__ bias) {
  int r = blockIdx.x, t = threadIdx.x;
  const float* src; float bval;
  if (r < 32)      { src = Wq + (r << 8);        bval = bq[r]; }
  else if (r < 64) { src = Wk + ((r - 32) << 8); bval = bk[r - 32]; }
  else             { src = Wv + ((r - 64) << 8); bval = bv[r - 64]; }
  wt[(r << 8) + t] = (bf16)src[t];
  if (t == 0) bias[r] = bval;
}

// ---------------- kernel 1: fused avgpool(4x4) + q/k/v 1x1-conv GEMM (MFMA)
__global__ __launch_bounds__(1024) void k_fused(const float* __restrict__ x,
    const bf16* __restrict__ wt, const float* __restrict__ bias,
    bf16* __restrict__ qt, bf16* __restrict__ kt, bf16* __restrict__ v) {
  __shared__ bf16 xsb[64][264];   // [n][c], +8 pad
  int tid = threadIdx.x, wave = tid >> 6, l = tid & 63;
  int lg = l >> 4, ll = l & 15;
  int b = blockIdx.x >> 6, hp = blockIdx.x & 63, n0 = hp * 64;

  const float4* x4 = reinterpret_cast<const float4*>(x) +
      ((size_t)((b * 256 + wave * 16) * 256 + hp * 4)) * 64 + l;
  for (int c0 = 0; c0 < 16; c0 += 4) {
    float s[4] = {0.f, 0.f, 0.f, 0.f};
    #pragma unroll
    for (int j = 0; j < 4; ++j) {
      const float4* p = x4 + (size_t)(c0 + j) * 16384;
      #pragma unroll
      for (int dh = 0; dh < 4; ++dh) {
        float4 a = p[dh * 64];
        s[j] += a.x + a.y + a.z + a.w;
      }
    }
    bf16x4 pk;
    #pragma unroll
    for (int j = 0; j < 4; ++j) pk[j] = (bf16)(s[j] * 0.0625f);
    *reinterpret_cast<bf16x4*>(&xsb[l][wave * 16 + c0]) = pk;
  }
  __syncthreads();

  f32x4 acc[2][4];
  #pragma unroll
  for (int j = 0; j < 2; ++j)
    #pragma unroll
    for (int cb = 0; cb < 4; ++cb) acc[j][cb] = (f32x4){0.f, 0.f, 0.f, 0.f};

  for (int kk = 0; kk < 8; ++kk) {
    bf16x8 bfr[4];
    #pragma unroll
    for (int cb = 0; cb < 4; ++cb)
      bfr[cb] = *reinterpret_cast<const bf16x8*>(&xsb[cb * 16 + ll][kk * 32 + lg * 8]);
    #pragma unroll
    for (int j = 0; j < 2; ++j) {
      int rb = wave + j * 16;
      if (rb < 20) {
        bf16x8 afr = *reinterpret_cast<const bf16x8*>(
            wt + ((size_t)(rb * 16 + ll)) * 256 + kk * 32 + lg * 8);
        #pragma unroll
        for (int cb = 0; cb < 4; ++cb)
          acc[j][cb] = __builtin_amdgcn_mfma_f32_16x16x32_bf16(afr, bfr[cb], acc[j][cb], 0, 0, 0);
      }
    }
  }

  #pragma unroll
  for (int j = 0; j < 2; ++j) {
    int rb = wave + j * 16;
    if (rb < 20) {
      int row0 = rb * 16 + lg * 4;
      float4 b4 = *reinterpret_cast<const float4*>(bias + row0);
      #pragma unroll
      for (int cb = 0; cb < 4; ++cb) {
        int n = n0 + cb * 16 + ll;
        float v0 = acc[j][cb][0] + b4.x, v1 = acc[j][cb][1] + b4.y;
        float v2 = acc[j][cb][2] + b4.z, v3 = acc[j][cb][3] + b4.w;
        if (row0 < 32) {
          bf16x4 pk = {(bf16)v0, (bf16)v1, (bf16)v2, (bf16)v3};
          *reinterpret_cast<bf16x4*>(qt + ((size_t)(b * N_ + n)) * D_ + row0) = pk;
        } else if (row0 < 64) {
          bf16x4 pk = {(bf16)v0, (bf16)v1, (bf16)v2, (bf16)v3};
          *reinterpret_cast<bf16x4*>(kt + ((size_t)(b * N_ + n)) * D_ + row0 - 32) = pk;
        } else {
          int c = row0 - 64;
          v[((size_t)(b * 256 + c + 0)) * N_ + n] = (bf16)v0;
          v[((size_t)(b * 256 + c + 1)) * N_ + n] = (bf16)v1;
          v[((size_t)(b * 256 + c + 2)) * N_ + n] = (bf16)v2;
          v[((size_t)(b * 256 + c + 3)) * N_ + n] = (bf16)v3;
        }
      }
    }
  }
}

// ---------------- kernel 3: flash-style attention, bf16 MFMA, double-buffered.
// Phase B = R5 structure (1 v-load : 4 MFMA). Swapped QK^T (mfma(K,Q)) ->
// P stores are ds_write_b64; P layout unpadded [64][256] with 16B-block
// XOR swizzle blk' = blk ^ (row&7) -> conflict-free ds_read_b128 in PV.
__global__ __launch_bounds__(1024) void k_attn(const bf16* __restrict__ qt,
    const bf16* __restrict__ kt, const bf16* __restrict__ v,
    float* __restrict__ outs) {
  __shared__ bf16 p_s[2][64][256];       // [buf][tn][tm], swizzled 16B blocks
  __shared__ float l_red[16][64];
  __shared__ float l_s[64];
  int tid = threadIdx.x, wave = tid >> 6, l = tid & 63;
  int lg = l >> 4, ll = l & 15;
  int blk = blockIdx.x;
  int b  = (blk & 7) >> 1;                       // XCD-pair -> batch (L2 locality)
  int nt = ((blk >> 3) << 1) | (blk & 1);        // 64 query tiles of 64
  int n0 = nt * 64;

  const f32x4 fz = {0.f, 0.f, 0.f, 0.f};

  bf16x8 aq[4];
  #pragma unroll
  for (int tnf = 0; tnf < 4; ++tnf)
    aq[tnf] = *reinterpret_cast<const bf16x8*>(
        qt + ((size_t)(b * N_ + n0 + tnf * 16 + ll)) * D_ + lg * 8);

  f32x4 acc[4];      // [tnf] : out tile [64tn x 16c per wave]
  float lsum[4];     // [tnf] row-sum partial for tn = tnf*16+ll (this wave's m band)
  #pragma unroll
  for (int a = 0; a < 4; ++a) { acc[a] = fz; lsum[a] = 0.f; }

  const int mw = wave * 16;   // QK^T tm band == PV c band
  const int colw = mw + ll;
  const bf16* vbase = v + ((size_t)(b << 8)) * N_;

  // phase-A store geometry: row = tn = tnf*16+ll; tm base = mw + lg*4.
  // 16B block index of tm = 2*wave + (lg>>1); element-in-block = (lg&1)*4.
  const int st_blk = 2 * wave + (lg >> 1);
  const int st_el  = (lg & 1) * 4;

  // ---- prologue: A(0) into p_s[0]  (E^T = mfma(K,Q): D[tm][tn])
  {
    bf16x8 bk8 = *reinterpret_cast<const bf16x8*>(
        kt + ((size_t)(b * N_ + colw)) * D_ + lg * 8);
    #pragma unroll
    for (int tnf = 0; tnf < 4; ++tnf) {
      f32x4 e = __builtin_amdgcn_mfma_f32_16x16x32_bf16(bk8, aq[tnf], fz, 0, 0, 0);
      int row = tnf * 16 + ll;
      bf16x4 pk;
      #pragma unroll
      for (int r = 0; r < 4; ++r) {
        float p = __expf(e[r]);
        lsum[tnf] += p;
        pk[r] = (bf16)p;
      }
      int col = ((st_blk ^ (row & 7)) << 3) + st_el;
      *reinterpret_cast<bf16x4*>(&p_s[0][row][col]) = pk;
    }
  }
  __syncthreads();

  // ---- main loop: B(t) || A(t+1), one barrier per iter
  for (int t = 0; t < 15; ++t) {
    int m0 = t * 256;
    int cur = t & 1, nxt = cur ^ 1;
    bf16x8 bk8 = *reinterpret_cast<const bf16x8*>(
        kt + ((size_t)(b * N_ + m0 + 256 + colw)) * D_ + lg * 8);
    // B(t): O[64tn x 16c] over m in [m0, m0+256); pa swizzled read
    #pragma unroll
    for (int kk = 0; kk < 8; ++kk) {
      bf16x8 bv8 = *reinterpret_cast<const bf16x8*>(
          vbase + ((size_t)colw) * N_ + m0 + kk * 32 + lg * 8);
      #pragma unroll
      for (int tnf = 0; tnf < 4; ++tnf) {
        int row = tnf * 16 + ll;
        int col = (((kk * 4 + lg) ^ (ll & 7)) << 3);
        bf16x8 pa = *reinterpret_cast<const bf16x8*>(&p_s[cur][row][col]);
        acc[tnf] = __builtin_amdgcn_mfma_f32_16x16x32_bf16(pa, bv8, acc[tnf], 0, 0, 0);
      }
    }
    // A(t+1)
    #pragma unroll
    for (int tnf = 0; tnf < 4; ++tnf) {
      f32x4 e = __builtin_amdgcn_mfma_f32_16x16x32_bf16(bk8, aq[tnf], fz, 0, 0, 0);
      int row = tnf * 16 + ll;
      bf16x4 pk;
      #pragma unroll
      for (int r = 0; r < 4; ++r) {
        float p = __expf(e[r]);
        lsum[tnf] += p;
        pk[r] = (bf16)p;
      }
      int col = ((st_blk ^ (row & 7)) << 3) + st_el;
      *reinterpret_cast<bf16x4*>(&p_s[nxt][row][col]) = pk;
    }
    __syncthreads();
  }
  // ---- tail: B(15) from p_s[1]
  {
    int m0 = 15 * 256;
    #pragma unroll
    for (int kk = 0; kk < 8; ++kk) {
      bf16x8 bv8 = *reinterpret_cast<const bf16x8*>(
          vbase + ((size_t)colw) * N_ + m0 + kk * 32 + lg * 8);
      #pragma unroll
      for (int tnf = 0; tnf < 4; ++tnf) {
        int row = tnf * 16 + ll;
        int col = (((kk * 4 + lg) ^ (ll & 7)) << 3);
        bf16x8 pa = *reinterpret_cast<const bf16x8*>(&p_s[1][row][col]);
        acc[tnf] = __builtin_amdgcn_mfma_f32_16x16x32_bf16(pa, bv8, acc[tnf], 0, 0, 0);
      }
    }
  }

  // ---- reduce l: lane holds partial for tn = tnf*16+ll over its m band.
  #pragma unroll
  for (int tnf = 0; tnf < 4; ++tnf) {
    float s = lsum[tnf];
    s += __shfl_xor(s, 16);
    s += __shfl_xor(s, 32);
    if (l < 16) l_red[wave][tnf * 16 + l] = s;
  }
  __syncthreads();
  if (tid < 64) {
    float s = 0.f;
    #pragma unroll
    for (int w = 0; w < 16; ++w) s += l_red[w][tid];
    l_s[tid] = s;
  }
  __syncthreads();

  // ---- normalize + write outs[b][c][n] (float4 over contiguous n)
  #pragma unroll
  for (int tnf = 0; tnf < 4; ++tnf) {
    int tn0 = tnf * 16 + lg * 4;
    float4 o;
    o.x = acc[tnf][0] / l_s[tn0 + 0];
    o.y = acc[tnf][1] / l_s[tn0 + 1];
    o.z = acc[tnf][2] / l_s[tn0 + 2];
    o.w = acc[tnf][3] / l_s[tn0 + 3];
    *reinterpret_cast<float4*>(outs + ((size_t)((b << 8) + colw)) * N_ + n0 + tn0) = o;
  }
}

// ---------------- kernel 4: bilinear upsample x4 + gamma residual.
__global__ __launch_bounds__(256) void k_up(const float* __restrict__ outs,
    const float* __restrict__ x, const float* __restrict__ gamma,
    float* __restrict__ out) {
  __shared__ float s_o[4096];            // outs[bc] as [64][64]
  int tid = threadIdx.x, wave = tid >> 6, tw = tid & 63;
  int bc = blockIdx.x;
  const float* src = outs + (size_t)bc * 4096;
  #pragma unroll
  for (int ch = 0; ch < 4; ++ch)
    *reinterpret_cast<float4*>(&s_o[ch * 1024 + tid * 4]) =
        *reinterpret_cast<const float4*>(src + ch * 1024 + tid * 4);
  __syncthreads();

  float g = gamma[0];
  const float4* xr = reinterpret_cast<const float4*>(x) + (size_t)bc * 16384;
  float4* outr = reinterpret_cast<float4*>(out) + (size_t)bc * 16384;

  int twm = tw == 0 ? 0 : tw - 1;
  int twp = tw == 63 ? 63 : tw + 1;

  for (int hb = 0; hb < 64; ++hb) {
    int h = hb * 4 + wave;
    int th = 2 * h - 3;
    int h0 = th < 0 ? -1 : (th >> 3);
    float fh = (float)(th - 8 * h0) * 0.125f;
    int i0h = h0 < 0 ? 0 : h0;
    int i1h = h0 + 1 > 63 ? 63 : h0 + 1;
    const float* r0 = &s_o[i0h * 64];
    const float* r1 = &s_o[i1h * 64];
    float a_m = r0[twm], a_c = r0[tw], a_p = r0[twp];
    float b_m = r1[twm], b_c = r1[tw], b_p = r1[twp];
    float t0 = a_m + 0.625f * (a_c - a_m), u0 = b_m + 0.625f * (b_c - b_m);
    float t1 = a_m + 0.875f * (a_c - a_m), u1 = b_m + 0.875f * (b_c - b_m);
    float t2 = a_c + 0.125f * (a_p - a_c), u2 = b_c + 0.125f * (b_p - b_c);
    float t3 = a_c + 0.375f * (a_p - a_c), u3 = b_c + 0.375f * (b_p - b_c);
    float4 xv = xr[h * 64 + tw];
    float4 o;
    o.x = g * (t0 + fh * (u0 - t0)) + xv.x;
    o.y = g * (t1 + fh * (u1 - t1)) + xv.y;
    o.z = g * (t2 + fh * (u2 - t2)) + xv.z;
    o.w = g * (t3 + fh * (u3 - t3)) + xv.w;
    outr[h * 64 + tw] = o;
  }
}

extern "C" void kernel_launch(void* const* d_in, const int* in_sizes, int n_in,
                              void* d_out, int out_size, void* d_ws, size_t ws_size,
                              hipStream_t stream) {
  const float* x     = (const float*)d_in[0];
  const float* Wq    = (const float*)d_in[1];
  const float* bq    = (const float*)d_in[2];
  const float* Wk    = (const float*)d_in[3];
  const float* bk    = (const float*)d_in[4];
  const float* Wv    = (const float*)d_in[5];
  const float* bv    = (const float*)d_in[6];
  const float* gamma = (const float*)d_in[7];
  float* out = (float*)d_out;

  char* ws = (char*)d_ws;
  float* outs = (float*)(ws);                         // 16 MiB
  bf16*  v    = (bf16*) (ws + (16u << 20));           // 8 MiB
  bf16*  qt   = (bf16*) (ws + (24u << 20));           // 1 MiB
  bf16*  kt   = (bf16*) (ws + (25u << 20));           // 1 MiB
  bf16*  wt   = (bf16*) (ws + (26u << 20));           // 160 KiB
  float* bias = (float*)(ws + (27u << 20));           // 1.25 KiB

  hipLaunchKernelGGL(k_prep,  dim3(320),  dim3(256),  0, stream,
                     Wq, bq, Wk, bk, Wv, bv, wt, bias);
  hipLaunchKernelGGL(k_fused, dim3(256),  dim3(1024), 0, stream,
                     x, wt, bias, qt, kt, v);
  hipLaunchKernelGGL(k_attn,  dim3(256),  dim3(1024), 0, stream, qt, kt, v, outs);
  hipLaunchKernelGGL(k_up,    dim3(1024), dim3(256),  0, stream, outs, x, gamma, out);
}